// Round 6
// baseline (1627.161 us; speedup 1.0000x reference)
//
#include <hip/hip_runtime.h>
#include <hip/hip_fp16.h>

// FixedFreqModel: B=512, L=2048, M=256, H=64, VOCAB=64, READ_FREQ=16.
// R18 = R17 (1190us steady) + two exposed-latency removals:
//  1. ALL 48 G-row loads + 4 token int4s hoisted to chunk top as named
//     scalars; GRU tail fully unrolled (16 steps) referencing them
//     statically. G latency (~200cy x 4 groups, previously exposed at each
//     group top) now hides under the ~2700cy attention phase. No rotation
//     queues, no cross-chunk live ranges, no copies (R14's failure modes).
//     At 1 wave/SIMD the +~50 VGPR cost is free (512-reg budget).
//  2. v-loop split into 4 accumulators (chain depth 128 -> 32), combined
//     ((r0+r1)+(r2+r3))*inv. Ulp-level reassociation of already-fp16-rounded
//     products; ~250cy/chunk latency removed.
// Weights W_hh + WR register-resident (R16). No pins, no waves_per_eu.

#define B_ 512
#define L_ 2048
#define M_ 256
#define H_ 64
#define C_ 128
#define F_ 16

typedef float v2f __attribute__((ext_vector_type(2)));
typedef _Float16 h2v __attribute__((ext_vector_type(2)));

#if __has_builtin(__builtin_amdgcn_fdot2)
__device__ __forceinline__ float FDOT2(h2v a, h2v b, float c) {
    return __builtin_amdgcn_fdot2(a, b, c, false);
}
#else
__device__ __forceinline__ float FDOT2(h2v a, h2v b, float c) {
    return c + (float)a[0]*(float)b[0] + (float)a[1]*(float)b[1];
}
#endif

__device__ __forceinline__ h2v bch(unsigned u) { return __builtin_bit_cast(h2v, u); }
__device__ __forceinline__ unsigned rl_u(unsigned v, int lane) {
    return (unsigned)__builtin_amdgcn_readlane((int)v, lane);
}
__device__ __forceinline__ float rl(float v, int lane) {
    return __int_as_float(__builtin_amdgcn_readlane(__float_as_int(v), lane));
}
// pack (mine, neighbor) -> half2 in lane order (even idx first)
__device__ __forceinline__ unsigned packpair(float mine, float other, bool odd) {
    float lo = odd ? other : mine;
    float hi = odd ? mine : other;
    auto r = __builtin_amdgcn_cvt_pkrtz(lo, hi);   // __fp16 ext_vector(2)
    return __builtin_bit_cast(unsigned, r);
}
__device__ __forceinline__ unsigned pkrtz(float a, float b) {
    auto r = __builtin_amdgcn_cvt_pkrtz(a, b);
    return __builtin_bit_cast(unsigned, r);
}
__device__ __forceinline__ float dot4(float4 a, float4 b) {
    return a.x*b.x + a.y*b.y + a.z*b.z + a.w*b.w;
}
__device__ __forceinline__ float fast_rcp(float x) { return __builtin_amdgcn_rcpf(x); }
__device__ __forceinline__ float sigm(float x) { return fast_rcp(1.f + __expf(-x)); }
__device__ __forceinline__ float tanh_f(float x) {
    float e2 = __expf(-2.f * fabsf(x));
    return copysignf((1.f - e2) * fast_rcp(1.f + e2), x);
}
__device__ __forceinline__ unsigned h2rn(float a, float b) {
    __half2 h = __floats2half2_rn(a, b);
    return __builtin_bit_cast(unsigned, h);
}

// workspace offsets (bytes)
#define WS_KT    0u            // kT2: 512 * 8192 u32 = 16 MB  [b][hh2][m]
#define WS_V     16777216u     // vT2: 512 * 8192 u32 = 16 MB  [b][o][mp]
#define WS_G     33554432u     // 64*192 fp32 = 48 KB
#define WS_WPHH  33603584u     // 6144 u32 = 24 KB  [(k2*3+g)*64+j]
#define WS_WR    33628160u     // 6144 u32 = 24 KB
#define WS_QP    33652736u     // 2048 u32 = 8 KB   [k2*64+j]
#define WS_KWP   33660928u     // 1024 float4 = 16 KB
#define WS_VWP   33677312u     // 16 KB

// dynamic LDS layout (bytes)
#define S_KT   0u        // 32768 : kT2 u32 [hh2=32][m=256]  (uint4 per (hh2, 4m))
#define S_V    32768u    // 33792 : vP u32 [o=64][132] (128 mp-pairs + 4 pad)
#define S_QP   66560u    // 8192  : QP2 u32 [k2=32][j=64]
#define S_P    74752u    // 512   : p fp16 pairs u32 [mp=128]
#define SMEM_BYTES 75264u

// ---------------- pack weights -----------------------------------------------
__global__ void pack_weights(const float* __restrict__ w_ih,
                             const float* __restrict__ w_hh,
                             const float* __restrict__ qw,
                             const float* __restrict__ kw,
                             const float* __restrict__ vw,
                             unsigned* __restrict__ WPhh2,
                             unsigned* __restrict__ WR2p,
                             unsigned* __restrict__ QP2,
                             float4* __restrict__ KWP,
                             float4* __restrict__ VWP)
{
    int idx = blockIdx.x * 256 + threadIdx.x;
    if (idx < 6144) {                        // WPhh2[(k2*3+g)*64+j]
        int j = idx & 63, t = idx >> 6, g = t % 3, k2 = t / 3;
        const float* s = w_hh + (g*64 + j)*64 + 2*k2;
        WPhh2[idx] = h2rn(s[0], s[1]);
    } else if (idx < 12288) {                // WR2p: retrieved half of w_ih
        int i = idx - 6144;
        int j = i & 63, t = i >> 6, g = t % 3, k2 = t / 3;
        const float* s = w_ih + (g*64 + j)*128 + 64 + 2*k2;
        WR2p[i] = h2rn(s[0], s[1]);
    } else if (idx < 14336) {                // QP2[k2*64+j]
        int i = idx - 12288;
        int j = i & 63, k2 = i >> 6;
        const float* s = qw + j*64 + 2*k2;
        QP2[i] = h2rn(s[0], s[1]);
    } else if (idx < 15360) {
        int i = idx - 14336;
        int j = i & 63, k4 = i >> 6;
        const float* s = kw + j*64 + 4*k4;
        KWP[i] = make_float4(s[0], s[1], s[2], s[3]);
    } else if (idx < 16384) {
        int i = idx - 15360;
        int j = i & 63, k4 = i >> 6;
        const float* s = vw + j*64 + 4*k4;
        VWP[i] = make_float4(s[0], s[1], s[2], s[3]);
    }
}

// ---------------- G[v][o] = sum_k embed[v][k]*w_ih[o][k] + b_ih[o] ----------
__global__ __launch_bounds__(64) void build_G(const float* __restrict__ embed_w,
                                              const float* __restrict__ w_ih,
                                              const float* __restrict__ b_ih,
                                              float* __restrict__ G)
{
    int v = blockIdx.x, j = threadIdx.x;
    __shared__ float e_s[64];
    e_s[j] = embed_w[v*64 + j];
    __syncthreads();
    float a0 = b_ih[j], a1 = b_ih[64 + j], a2 = b_ih[128 + j];
    for (int k = 0; k < 64; ++k) {
        float e = e_s[k];
        a0 += e * w_ih[j*128 + k];
        a1 += e * w_ih[(64 + j)*128 + k];
        a2 += e * w_ih[(128 + j)*128 + k];
    }
    G[v*192 + j]       = a0;
    G[v*192 + 64 + j]  = a1;
    G[v*192 + 128 + j] = a2;
}

// ------- k/v precompute (kT hh-pair u32; v m-pair-transposed u32) ------------
__global__ __launch_bounds__(256) void compute_kv(const float* __restrict__ memory,
                                                  const float* __restrict__ key_b,
                                                  const float* __restrict__ val_b,
                                                  const float4* __restrict__ KWP,
                                                  const float4* __restrict__ VWP,
                                                  unsigned* __restrict__ kT2,
                                                  unsigned* __restrict__ vT2)
{
    int wid = threadIdx.x >> 6;
    int o   = threadIdx.x & 63;
    int row = blockIdx.x * 4 + wid;          // row = b*256 + m
    int b = row >> 8, m = row & 255;
    __shared__ __align__(16) float mem_s[4][64];
    __shared__ float avs[4][64];
    mem_s[wid][o] = memory[(size_t)row * 64 + o];
    __syncthreads();
    float ak = key_b[o], av = val_b[o];
    const float4* m4 = (const float4*)mem_s[wid];
#pragma unroll
    for (int k4 = 0; k4 < 16; ++k4) {
        float4 mm = m4[k4];
        ak += dot4(mm, KWP[k4*64 + o]);
        av += dot4(mm, VWP[k4*64 + o]);
    }
    float nb = __shfl_xor(ak, 1);            // k[o^1][m]
    if ((o & 1) == 0)                        // pair (k[o][m], k[o+1][m])
        kT2[((size_t)b*32 + (o >> 1))*256 + m] = h2rn(ak, nb);
    avs[wid][o] = av;
    __syncthreads();
    if ((wid & 1) == 0) {                    // pair (v[m][o], v[m+1][o]), m even
        vT2[((size_t)b*64 + o)*128 + (m >> 1)] = h2rn(avs[wid][o], avs[wid+1][o]);
    }
}

// one GRU step: h broadcast as half2 via readlane; dot2 matvec; no LDS
#define GRU_STEP(cg0, cg1, cg2) do {                                        \
    float gr = (cg0) + RrB, gz = (cg1) + RzB, gn = bhn;                     \
    _Pragma("unroll")                                                       \
    for (int kp = 0; kp < 32; ++kp) {                                       \
        h2v hhp = bch(rl_u(hpu, 2*kp));                                     \
        gr = FDOT2(hhp, wr2[kp], gr);                                       \
        gz = FDOT2(hhp, wz2[kp], gz);                                       \
        gn = FDOT2(hhp, wn2[kp], gn);                                       \
    }                                                                       \
    float r_ = sigm(gr);                                                    \
    float z_ = sigm(gz);                                                    \
    float n_ = tanh_f(((cg2) + Rn) + r_ * gn);                              \
    h = fmaf(z_, h - n_, n_);                                               \
    float hx_ = __shfl_xor(h, 1);                                           \
    hpu = packpair(h, hx_, odd);                                            \
} while (0)

// load one G row triple into named floats (issued at chunk top)
#define LDG(nm, tok)                                                        \
    const float* P##nm = G + (tok)*192;                                     \
    float nm##0 = P##nm[j], nm##1 = P##nm[64+j], nm##2 = P##nm[128+j];

// ---------------- main recurrent kernel: 1 wave per batch element ------------
__global__ __launch_bounds__(64, 1) void recurrent_main(
    const int*   __restrict__ seq,
    const float* __restrict__ b_hh,
    const float* __restrict__ query_b,
    const float* __restrict__ head_w,
    const float* __restrict__ head_b,
    const unsigned* __restrict__ kT2g,
    const unsigned* __restrict__ vT2g,
    const float* __restrict__ G,
    const unsigned* __restrict__ WPhh2,
    const unsigned* __restrict__ WR2p,
    const unsigned* __restrict__ QP2g,
    float* __restrict__ out)
{
    const int b = blockIdx.x;
    const int j = threadIdx.x;
    const bool odd = (j & 1);

    extern __shared__ __align__(16) char smem[];
    const uint4* kT2_lds = (const uint4*)(smem + S_KT);  // [hh2*64 + j]: 4 m-pairs
    const unsigned* qp2  = (const unsigned*)(smem + S_QP); // [k2*64 + j]

    // ---- stage kT2, vT2 (repad 128->132 u32 rows), QP2 into LDS once ----
    {
        const uint4* kTg = (const uint4*)(kT2g + (size_t)b * 8192);
        uint4* kTls = (uint4*)(smem + S_KT);
#pragma unroll
        for (int i = 0; i < 32; ++i) kTls[i*64 + j] = kTg[i*64 + j];
        const uint4* vg4 = (const uint4*)(vT2g + (size_t)b * 8192);
        uint4* vls4 = (uint4*)(smem + S_V);
#pragma unroll
        for (int i = 0; i < 32; ++i) {
            int t = i*64 + j;                 // global quad: o = t>>5, q = t&31
            vls4[(t >> 5)*33 + (t & 31)] = vg4[t];
        }
        const uint4* qpg = (const uint4*)QP2g;
        uint4* qls = (uint4*)(smem + S_QP);
#pragma unroll
        for (int i = 0; i < 8; ++i) qls[i*64 + j] = qpg[i*64 + j];
    }

    // ---- W_hh in registers as half2: 96 words (compiler parks in AGPRs) ----
    h2v wr2[32], wz2[32], wn2[32];
#pragma unroll
    for (int k2 = 0; k2 < 32; ++k2) {
        wr2[k2] = bch(WPhh2[(k2*3 + 0)*64 + j]);
        wz2[k2] = bch(WPhh2[(k2*3 + 1)*64 + j]);
        wn2[k2] = bch(WPhh2[(k2*3 + 2)*64 + j]);
    }
    // ---- WR (retrieved-half of w_ih) likewise: 96 words, loaded ONCE ----
    h2v rr2[32], rz2[32], rn2[32];
#pragma unroll
    for (int k2 = 0; k2 < 32; ++k2) {
        rr2[k2] = bch(WR2p[(k2*3 + 0)*64 + j]);
        rz2[k2] = bch(WR2p[(k2*3 + 1)*64 + j]);
        rn2[k2] = bch(WR2p[(k2*3 + 2)*64 + j]);
    }

    float h = 0.f;                       // lane j owns h[j]; never leaves regs
    unsigned hpu = 0u;                   // packed (h[2t], h[2t+1]) fp16 pair
    const float bhr = b_hh[j], bhz = b_hh[64 + j], bhn = b_hh[128 + j];
    const float qb  = query_b[j];

    const int* seqb = seq + (size_t)b * L_;
    const uint4* vrow = (const uint4*)(smem + S_V) + j*33;   // lane's o-row
    const uint4* p4   = (const uint4*)(smem + S_P);
    __builtin_amdgcn_wave_barrier();

    for (int c = 0; c < C_; ++c) {
        const int c16 = c * F_;

        // ---- chunk top: tokens + ALL 48 G loads (hidden under attention) ----
        const int4 pA = *(const int4*)(seqb + c16);
        const int4 pB = *(const int4*)(seqb + c16 + 4);
        const int4 pC = *(const int4*)(seqb + c16 + 8);
        const int4 pD = *(const int4*)(seqb + c16 + 12);
        LDG(tA, pA.x) LDG(tB, pA.y) LDG(tC, pA.z) LDG(tD, pA.w)
        LDG(tE, pB.x) LDG(tF, pB.y) LDG(tG, pB.z) LDG(tH, pB.w)
        LDG(tI, pC.x) LDG(tJ, pC.y) LDG(tK, pC.z) LDG(tL, pC.w)
        LDG(tM, pD.x) LDG(tN, pD.y) LDG(tO, pD.z) LDG(tP, pD.w)

        // ---- q[j] = qb + sum_k h[k]*Wq[j][k]  (dot2: h pairs + QP2 LDS) ----
        float q = qb;
#pragma unroll 8
        for (int k2 = 0; k2 < 32; ++k2) {
            h2v pp = bch(qp2[k2*64 + j]);
            h2v hh = bch(rl_u(hpu, 2*k2));
            q = FDOT2(hh, pp, q);
        }

        // ---- scores: lane j owns m = 4j..4j+3 (dot2 over hh-pairs) ----
        float qx = __shfl_xor(q, 1);
        unsigned qpu = packpair(q, qx, odd);
        float s0 = 0.f, s1 = 0.f, s2 = 0.f, s3 = 0.f;
#pragma unroll 8
        for (int t = 0; t < 32; ++t) {
            h2v qq = bch(rl_u(qpu, 2*t));
            uint4 kk = kT2_lds[t*64 + j];
            s0 = FDOT2(bch(kk.x), qq, s0);
            s1 = FDOT2(bch(kk.y), qq, s1);
            s2 = FDOT2(bch(kk.z), qq, s2);
            s3 = FDOT2(bch(kk.w), qq, s3);
        }
        const float scale = 0.125f;
        // softmax, no max-sub (|s| small), rcp not div
        float4 p;
        p.x = __expf(s0*scale); p.y = __expf(s1*scale);
        p.z = __expf(s2*scale); p.w = __expf(s3*scale);
        float sum = (p.x + p.y) + (p.z + p.w);
#pragma unroll
        for (int o = 32; o > 0; o >>= 1) sum += __shfl_xor(sum, o);
        float inv = fast_rcp(sum);
        // p as fp16 pairs (unnormalized): mp=2j -> (p[4j],p[4j+1]); 2j+1 -> ...
        *(uint2*)(smem + S_P + (size_t)j*8) =
            make_uint2(pkrtz(p.x, p.y), pkrtz(p.z, p.w));
        __builtin_amdgcn_wave_barrier();

        // ---- retrieved: lane j owns ret[j]; 4 accs (chain depth 32) ----
        float r0 = 0.f, r1 = 0.f, r2 = 0.f, r3 = 0.f;
#pragma unroll 8
        for (int qd = 0; qd < 32; ++qd) {
            uint4 vv = vrow[qd];          // pairs mp = 4qd..4qd+3 for o=j
            uint4 pp = p4[qd];            // broadcast
            r0 = FDOT2(bch(pp.x), bch(vv.x), r0);
            r1 = FDOT2(bch(pp.y), bch(vv.y), r1);
            r2 = FDOT2(bch(pp.z), bch(vv.z), r2);
            r3 = FDOT2(bch(pp.w), bch(vv.w), r3);
        }
        float ret = ((r0 + r1) + (r2 + r3)) * inv;

        // ---- R matvec: ret packed like h (pairs via shfl); WR in regs ----
        float rx = __shfl_xor(ret, 1);
        unsigned rpu = packpair(ret, rx, odd);
        float Rr = 0.f, Rz = 0.f, Rn = 0.f;
#pragma unroll
        for (int k2 = 0; k2 < 32; ++k2) {
            h2v rr = bch(rl_u(rpu, 2*k2));
            Rr = FDOT2(rr, rr2[k2], Rr);
            Rz = FDOT2(rr, rz2[k2], Rz);
            Rn = FDOT2(rr, rn2[k2], Rn);
        }
        const float RrB = Rr + bhr, RzB = Rz + bhz;

        // ---- 16 GRU steps, fully unrolled, all G values already in regs ----
        GRU_STEP(tA0, tA1, tA2);
        GRU_STEP(tB0, tB1, tB2);
        GRU_STEP(tC0, tC1, tC2);
        GRU_STEP(tD0, tD1, tD2);
        GRU_STEP(tE0, tE1, tE2);
        GRU_STEP(tF0, tF1, tF2);
        GRU_STEP(tG0, tG1, tG2);
        GRU_STEP(tH0, tH1, tH2);
        GRU_STEP(tI0, tI1, tI2);
        GRU_STEP(tJ0, tJ1, tJ2);
        GRU_STEP(tK0, tK1, tK2);
        GRU_STEP(tL0, tL1, tL2);
        GRU_STEP(tM0, tM1, tM2);
        GRU_STEP(tN0, tN1, tN2);
        GRU_STEP(tO0, tO1, tO2);
        GRU_STEP(tP0, tP1, tP2);
    }

    // ---- head: out[b][j] = head_b[j] + sum_k h[k]*head_w[j][k] (fp32) ----
    float o = head_b[j];
#pragma unroll
    for (int k4 = 0; k4 < 16; ++k4) {
        float h0 = rl(h, 4*k4+0), h1 = rl(h, 4*k4+1);
        float h2 = rl(h, 4*k4+2), h3 = rl(h, 4*k4+3);
        const float* hw = head_w + j*64 + 4*k4;
        o += h0*hw[0] + h1*hw[1] + h2*hw[2] + h3*hw[3];
    }
    out[(size_t)b*64 + j] = o;
}

extern "C" void kernel_launch(void* const* d_in, const int* in_sizes, int n_in,
                              void* d_out, int out_size, void* d_ws, size_t ws_size,
                              hipStream_t stream) {
    const int*   seq      = (const int*)  d_in[0];
    const float* memory   = (const float*)d_in[1];
    const float* embed_w  = (const float*)d_in[2];
    const float* w_ih     = (const float*)d_in[3];
    const float* w_hh     = (const float*)d_in[4];
    const float* b_ih     = (const float*)d_in[5];
    const float* b_hh     = (const float*)d_in[6];
    const float* key_w    = (const float*)d_in[7];
    const float* key_b    = (const float*)d_in[8];
    const float* val_w    = (const float*)d_in[9];
    const float* val_b    = (const float*)d_in[10];
    const float* query_w  = (const float*)d_in[11];
    const float* query_b  = (const float*)d_in[12];
    const float* head_w   = (const float*)d_in[13];
    const float* head_b   = (const float*)d_in[14];

    char* ws = (char*)d_ws;
    unsigned* kT2  = (unsigned*)(ws + WS_KT);
    unsigned* vT2  = (unsigned*)(ws + WS_V);
    float*    G    = (float*)   (ws + WS_G);
    unsigned* WPhh2 = (unsigned*)(ws + WS_WPHH);
    unsigned* WR2p  = (unsigned*)(ws + WS_WR);
    unsigned* QP2   = (unsigned*)(ws + WS_QP);
    float4*   KWP   = (float4*)  (ws + WS_KWP);
    float4*   VWP   = (float4*)  (ws + WS_VWP);

    (void)hipFuncSetAttribute((const void*)recurrent_main,
                              hipFuncAttributeMaxDynamicSharedMemorySize,
                              (int)SMEM_BYTES);

    pack_weights<<<64, 256, 0, stream>>>(w_ih, w_hh, query_w, key_w, val_w,
                                         WPhh2, WR2p, QP2, KWP, VWP);
    build_G<<<64, 64, 0, stream>>>(embed_w, w_ih, b_ih, G);
    compute_kv<<<(B_*M_)/4, 256, 0, stream>>>(memory, key_b, val_b, KWP, VWP, kT2, vT2);
    recurrent_main<<<B_, 64, SMEM_BYTES, stream>>>(seq, b_hh, query_b, head_w, head_b,
                                                   kT2, vT2, G, WPhh2, WR2p, QP2,
                                                   (float*)d_out);
}

// Round 7
// 1490.518 us; speedup vs baseline: 1.0917x; 1.0917x over previous
//
#include <hip/hip_runtime.h>
#include <hip/hip_fp16.h>

// FixedFreqModel: B=512, L=2048, M=256, H=64, VOCAB=64, READ_FREQ=16.
// R19 = R17 skeleton (1190us steady; 4-group GRU loop, I-cache-sized body,
// token hoist+cndmask) + accumulator-chain splitting:
//  - R18 post-mortem: full 16-step unroll blew I-cache (VALUBusy 29.5->24.9,
//    VGPR only +16 => compiler sank the hoisted G loads anyway). Reverted.
//  - Kept from R18: v-loop 4 accumulators (chain 128 -> 32).
//  - NEW: every serial dot2 accumulation chain split to break the
//    VOP3P-latency bound on the serial path (70% of cycles are stall):
//      GRU gr/gz/gn -> 2 chains each (6 interleaved chains/step),
//      q-matvec     -> 4 chains (was 1 chain of 32!),
//      R-matvec     -> 6 chains (was 3).
//    Ulp-level fp32 reassociation of fp16 products only.
// Weights W_hh + WR register-resident (R16). No pins, no waves_per_eu.

#define B_ 512
#define L_ 2048
#define M_ 256
#define H_ 64
#define C_ 128
#define F_ 16

typedef float v2f __attribute__((ext_vector_type(2)));
typedef _Float16 h2v __attribute__((ext_vector_type(2)));

#if __has_builtin(__builtin_amdgcn_fdot2)
__device__ __forceinline__ float FDOT2(h2v a, h2v b, float c) {
    return __builtin_amdgcn_fdot2(a, b, c, false);
}
#else
__device__ __forceinline__ float FDOT2(h2v a, h2v b, float c) {
    return c + (float)a[0]*(float)b[0] + (float)a[1]*(float)b[1];
}
#endif

__device__ __forceinline__ h2v bch(unsigned u) { return __builtin_bit_cast(h2v, u); }
__device__ __forceinline__ unsigned rl_u(unsigned v, int lane) {
    return (unsigned)__builtin_amdgcn_readlane((int)v, lane);
}
__device__ __forceinline__ float rl(float v, int lane) {
    return __int_as_float(__builtin_amdgcn_readlane(__float_as_int(v), lane));
}
// pack (mine, neighbor) -> half2 in lane order (even idx first)
__device__ __forceinline__ unsigned packpair(float mine, float other, bool odd) {
    float lo = odd ? other : mine;
    float hi = odd ? mine : other;
    auto r = __builtin_amdgcn_cvt_pkrtz(lo, hi);   // __fp16 ext_vector(2)
    return __builtin_bit_cast(unsigned, r);
}
__device__ __forceinline__ unsigned pkrtz(float a, float b) {
    auto r = __builtin_amdgcn_cvt_pkrtz(a, b);
    return __builtin_bit_cast(unsigned, r);
}
__device__ __forceinline__ float dot4(float4 a, float4 b) {
    return a.x*b.x + a.y*b.y + a.z*b.z + a.w*b.w;
}
__device__ __forceinline__ float fast_rcp(float x) { return __builtin_amdgcn_rcpf(x); }
__device__ __forceinline__ float sigm(float x) { return fast_rcp(1.f + __expf(-x)); }
__device__ __forceinline__ float tanh_f(float x) {
    float e2 = __expf(-2.f * fabsf(x));
    return copysignf((1.f - e2) * fast_rcp(1.f + e2), x);
}
__device__ __forceinline__ unsigned h2rn(float a, float b) {
    __half2 h = __floats2half2_rn(a, b);
    return __builtin_bit_cast(unsigned, h);
}

// workspace offsets (bytes)
#define WS_KT    0u            // kT2: 512 * 8192 u32 = 16 MB  [b][hh2][m]
#define WS_V     16777216u     // vT2: 512 * 8192 u32 = 16 MB  [b][o][mp]
#define WS_G     33554432u     // 64*192 fp32 = 48 KB
#define WS_WPHH  33603584u     // 6144 u32 = 24 KB  [(k2*3+g)*64+j]
#define WS_WR    33628160u     // 6144 u32 = 24 KB
#define WS_QP    33652736u     // 2048 u32 = 8 KB   [k2*64+j]
#define WS_KWP   33660928u     // 1024 float4 = 16 KB
#define WS_VWP   33677312u     // 16 KB

// dynamic LDS layout (bytes)
#define S_KT   0u        // 32768 : kT2 u32 [hh2=32][m=256]  (uint4 per (hh2, 4m))
#define S_V    32768u    // 33792 : vP u32 [o=64][132] (128 mp-pairs + 4 pad)
#define S_QP   66560u    // 8192  : QP2 u32 [k2=32][j=64]
#define S_P    74752u    // 512   : p fp16 pairs u32 [mp=128]
#define SMEM_BYTES 75264u

// ---------------- pack weights -----------------------------------------------
__global__ void pack_weights(const float* __restrict__ w_ih,
                             const float* __restrict__ w_hh,
                             const float* __restrict__ qw,
                             const float* __restrict__ kw,
                             const float* __restrict__ vw,
                             unsigned* __restrict__ WPhh2,
                             unsigned* __restrict__ WR2p,
                             unsigned* __restrict__ QP2,
                             float4* __restrict__ KWP,
                             float4* __restrict__ VWP)
{
    int idx = blockIdx.x * 256 + threadIdx.x;
    if (idx < 6144) {                        // WPhh2[(k2*3+g)*64+j]
        int j = idx & 63, t = idx >> 6, g = t % 3, k2 = t / 3;
        const float* s = w_hh + (g*64 + j)*64 + 2*k2;
        WPhh2[idx] = h2rn(s[0], s[1]);
    } else if (idx < 12288) {                // WR2p: retrieved half of w_ih
        int i = idx - 6144;
        int j = i & 63, t = i >> 6, g = t % 3, k2 = t / 3;
        const float* s = w_ih + (g*64 + j)*128 + 64 + 2*k2;
        WR2p[i] = h2rn(s[0], s[1]);
    } else if (idx < 14336) {                // QP2[k2*64+j]
        int i = idx - 12288;
        int j = i & 63, k2 = i >> 6;
        const float* s = qw + j*64 + 2*k2;
        QP2[i] = h2rn(s[0], s[1]);
    } else if (idx < 15360) {
        int i = idx - 14336;
        int j = i & 63, k4 = i >> 6;
        const float* s = kw + j*64 + 4*k4;
        KWP[i] = make_float4(s[0], s[1], s[2], s[3]);
    } else if (idx < 16384) {
        int i = idx - 15360;
        int j = i & 63, k4 = i >> 6;
        const float* s = vw + j*64 + 4*k4;
        VWP[i] = make_float4(s[0], s[1], s[2], s[3]);
    }
}

// ---------------- G[v][o] = sum_k embed[v][k]*w_ih[o][k] + b_ih[o] ----------
__global__ __launch_bounds__(64) void build_G(const float* __restrict__ embed_w,
                                              const float* __restrict__ w_ih,
                                              const float* __restrict__ b_ih,
                                              float* __restrict__ G)
{
    int v = blockIdx.x, j = threadIdx.x;
    __shared__ float e_s[64];
    e_s[j] = embed_w[v*64 + j];
    __syncthreads();
    float a0 = b_ih[j], a1 = b_ih[64 + j], a2 = b_ih[128 + j];
    for (int k = 0; k < 64; ++k) {
        float e = e_s[k];
        a0 += e * w_ih[j*128 + k];
        a1 += e * w_ih[(64 + j)*128 + k];
        a2 += e * w_ih[(128 + j)*128 + k];
    }
    G[v*192 + j]       = a0;
    G[v*192 + 64 + j]  = a1;
    G[v*192 + 128 + j] = a2;
}

// ------- k/v precompute (kT hh-pair u32; v m-pair-transposed u32) ------------
__global__ __launch_bounds__(256) void compute_kv(const float* __restrict__ memory,
                                                  const float* __restrict__ key_b,
                                                  const float* __restrict__ val_b,
                                                  const float4* __restrict__ KWP,
                                                  const float4* __restrict__ VWP,
                                                  unsigned* __restrict__ kT2,
                                                  unsigned* __restrict__ vT2)
{
    int wid = threadIdx.x >> 6;
    int o   = threadIdx.x & 63;
    int row = blockIdx.x * 4 + wid;          // row = b*256 + m
    int b = row >> 8, m = row & 255;
    __shared__ __align__(16) float mem_s[4][64];
    __shared__ float avs[4][64];
    mem_s[wid][o] = memory[(size_t)row * 64 + o];
    __syncthreads();
    float ak = key_b[o], av = val_b[o];
    const float4* m4 = (const float4*)mem_s[wid];
#pragma unroll
    for (int k4 = 0; k4 < 16; ++k4) {
        float4 mm = m4[k4];
        ak += dot4(mm, KWP[k4*64 + o]);
        av += dot4(mm, VWP[k4*64 + o]);
    }
    float nb = __shfl_xor(ak, 1);            // k[o^1][m]
    if ((o & 1) == 0)                        // pair (k[o][m], k[o+1][m])
        kT2[((size_t)b*32 + (o >> 1))*256 + m] = h2rn(ak, nb);
    avs[wid][o] = av;
    __syncthreads();
    if ((wid & 1) == 0) {                    // pair (v[m][o], v[m+1][o]), m even
        vT2[((size_t)b*64 + o)*128 + (m >> 1)] = h2rn(avs[wid][o], avs[wid+1][o]);
    }
}

// one GRU step: h broadcast as half2 via readlane; dot2 matvec; no LDS.
// 6 interleaved accumulation chains (2 per gate) to beat dot2 latency.
#define GRU_STEP(cg0, cg1, cg2) do {                                        \
    float gr0 = (cg0) + RrB, gz0 = (cg1) + RzB, gn0 = bhn;                  \
    float gr1 = 0.f, gz1 = 0.f, gn1 = 0.f;                                  \
    _Pragma("unroll")                                                       \
    for (int kp = 0; kp < 16; ++kp) {                                       \
        h2v h0 = bch(rl_u(hpu, 4*kp));                                      \
        h2v h1 = bch(rl_u(hpu, 4*kp + 2));                                  \
        gr0 = FDOT2(h0, wr2[2*kp],   gr0);                                  \
        gr1 = FDOT2(h1, wr2[2*kp+1], gr1);                                  \
        gz0 = FDOT2(h0, wz2[2*kp],   gz0);                                  \
        gz1 = FDOT2(h1, wz2[2*kp+1], gz1);                                  \
        gn0 = FDOT2(h0, wn2[2*kp],   gn0);                                  \
        gn1 = FDOT2(h1, wn2[2*kp+1], gn1);                                  \
    }                                                                       \
    float r_ = sigm(gr0 + gr1);                                             \
    float z_ = sigm(gz0 + gz1);                                             \
    float n_ = tanh_f(((cg2) + Rn) + r_ * (gn0 + gn1));                     \
    h = fmaf(z_, h - n_, n_);                                               \
    float hx_ = __shfl_xor(h, 1);                                           \
    hpu = packpair(h, hx_, odd);                                            \
} while (0)

// ---------------- main recurrent kernel: 1 wave per batch element ------------
__global__ __launch_bounds__(64, 1) void recurrent_main(
    const int*   __restrict__ seq,
    const float* __restrict__ b_hh,
    const float* __restrict__ query_b,
    const float* __restrict__ head_w,
    const float* __restrict__ head_b,
    const unsigned* __restrict__ kT2g,
    const unsigned* __restrict__ vT2g,
    const float* __restrict__ G,
    const unsigned* __restrict__ WPhh2,
    const unsigned* __restrict__ WR2p,
    const unsigned* __restrict__ QP2g,
    float* __restrict__ out)
{
    const int b = blockIdx.x;
    const int j = threadIdx.x;
    const bool odd = (j & 1);

    extern __shared__ __align__(16) char smem[];
    const uint4* kT2_lds = (const uint4*)(smem + S_KT);  // [hh2*64 + j]: 4 m-pairs
    const unsigned* qp2  = (const unsigned*)(smem + S_QP); // [k2*64 + j]

    // ---- stage kT2, vT2 (repad 128->132 u32 rows), QP2 into LDS once ----
    {
        const uint4* kTg = (const uint4*)(kT2g + (size_t)b * 8192);
        uint4* kTls = (uint4*)(smem + S_KT);
#pragma unroll
        for (int i = 0; i < 32; ++i) kTls[i*64 + j] = kTg[i*64 + j];
        const uint4* vg4 = (const uint4*)(vT2g + (size_t)b * 8192);
        uint4* vls4 = (uint4*)(smem + S_V);
#pragma unroll
        for (int i = 0; i < 32; ++i) {
            int t = i*64 + j;                 // global quad: o = t>>5, q = t&31
            vls4[(t >> 5)*33 + (t & 31)] = vg4[t];
        }
        const uint4* qpg = (const uint4*)QP2g;
        uint4* qls = (uint4*)(smem + S_QP);
#pragma unroll
        for (int i = 0; i < 8; ++i) qls[i*64 + j] = qpg[i*64 + j];
    }

    // ---- W_hh in registers as half2: 96 words (compiler parks in AGPRs) ----
    h2v wr2[32], wz2[32], wn2[32];
#pragma unroll
    for (int k2 = 0; k2 < 32; ++k2) {
        wr2[k2] = bch(WPhh2[(k2*3 + 0)*64 + j]);
        wz2[k2] = bch(WPhh2[(k2*3 + 1)*64 + j]);
        wn2[k2] = bch(WPhh2[(k2*3 + 2)*64 + j]);
    }
    // ---- WR (retrieved-half of w_ih) likewise: 96 words, loaded ONCE ----
    h2v rr2[32], rz2[32], rn2[32];
#pragma unroll
    for (int k2 = 0; k2 < 32; ++k2) {
        rr2[k2] = bch(WR2p[(k2*3 + 0)*64 + j]);
        rz2[k2] = bch(WR2p[(k2*3 + 1)*64 + j]);
        rn2[k2] = bch(WR2p[(k2*3 + 2)*64 + j]);
    }

    float h = 0.f;                       // lane j owns h[j]; never leaves regs
    unsigned hpu = 0u;                   // packed (h[2t], h[2t+1]) fp16 pair
    const float bhr = b_hh[j], bhz = b_hh[64 + j], bhn = b_hh[128 + j];
    const float qb  = query_b[j];

    const int* seqb = seq + (size_t)b * L_;
    const uint4* vrow = (const uint4*)(smem + S_V) + j*33;   // lane's o-row
    const uint4* p4   = (const uint4*)(smem + S_P);
    __builtin_amdgcn_wave_barrier();

    for (int c = 0; c < C_; ++c) {
        const int c16 = c * F_;

        // ---- token hoist: all 4 group int4s issued at chunk top ----
        const int4 pA = *(const int4*)(seqb + c16);
        const int4 pB = *(const int4*)(seqb + c16 + 4);
        const int4 pC = *(const int4*)(seqb + c16 + 8);
        const int4 pD = *(const int4*)(seqb + c16 + 12);

        // ---- q[j] = qb + sum_k h[k]*Wq[j][k]  (4 chains) ----
        float q0 = qb, q1 = 0.f, q2 = 0.f, q3 = 0.f;
#pragma unroll
        for (int k8 = 0; k8 < 8; ++k8) {
            q0 = FDOT2(bch(rl_u(hpu, 8*k8+0)), bch(qp2[(4*k8+0)*64 + j]), q0);
            q1 = FDOT2(bch(rl_u(hpu, 8*k8+2)), bch(qp2[(4*k8+1)*64 + j]), q1);
            q2 = FDOT2(bch(rl_u(hpu, 8*k8+4)), bch(qp2[(4*k8+2)*64 + j]), q2);
            q3 = FDOT2(bch(rl_u(hpu, 8*k8+6)), bch(qp2[(4*k8+3)*64 + j]), q3);
        }
        float q = (q0 + q1) + (q2 + q3);

        // ---- scores: lane j owns m = 4j..4j+3 (4 chains already) ----
        float qx = __shfl_xor(q, 1);
        unsigned qpu = packpair(q, qx, odd);
        float s0 = 0.f, s1 = 0.f, s2 = 0.f, s3 = 0.f;
#pragma unroll 8
        for (int t = 0; t < 32; ++t) {
            h2v qq = bch(rl_u(qpu, 2*t));
            uint4 kk = kT2_lds[t*64 + j];
            s0 = FDOT2(bch(kk.x), qq, s0);
            s1 = FDOT2(bch(kk.y), qq, s1);
            s2 = FDOT2(bch(kk.z), qq, s2);
            s3 = FDOT2(bch(kk.w), qq, s3);
        }
        const float scale = 0.125f;
        // softmax, no max-sub (|s| small), rcp not div
        float4 p;
        p.x = __expf(s0*scale); p.y = __expf(s1*scale);
        p.z = __expf(s2*scale); p.w = __expf(s3*scale);
        float sum = (p.x + p.y) + (p.z + p.w);
#pragma unroll
        for (int o = 32; o > 0; o >>= 1) sum += __shfl_xor(sum, o);
        float inv = fast_rcp(sum);
        // p as fp16 pairs (unnormalized): mp=2j -> (p[4j],p[4j+1]); 2j+1 -> ...
        *(uint2*)(smem + S_P + (size_t)j*8) =
            make_uint2(pkrtz(p.x, p.y), pkrtz(p.z, p.w));
        __builtin_amdgcn_wave_barrier();

        // ---- retrieved: lane j owns ret[j]; 4 accs (chain depth 32) ----
        float r0 = 0.f, r1 = 0.f, r2 = 0.f, r3 = 0.f;
#pragma unroll 8
        for (int qd = 0; qd < 32; ++qd) {
            uint4 vv = vrow[qd];          // pairs mp = 4qd..4qd+3 for o=j
            uint4 pp = p4[qd];            // broadcast
            r0 = FDOT2(bch(pp.x), bch(vv.x), r0);
            r1 = FDOT2(bch(pp.y), bch(vv.y), r1);
            r2 = FDOT2(bch(pp.z), bch(vv.z), r2);
            r3 = FDOT2(bch(pp.w), bch(vv.w), r3);
        }
        float ret = ((r0 + r1) + (r2 + r3)) * inv;

        // ---- R matvec: ret packed like h; WR in regs; 6 chains ----
        float rx = __shfl_xor(ret, 1);
        unsigned rpu = packpair(ret, rx, odd);
        float Rr0 = 0.f, Rr1 = 0.f, Rz0 = 0.f, Rz1 = 0.f, Rn0 = 0.f, Rn1 = 0.f;
#pragma unroll
        for (int kp = 0; kp < 16; ++kp) {
            h2v ra = bch(rl_u(rpu, 4*kp));
            h2v rb = bch(rl_u(rpu, 4*kp + 2));
            Rr0 = FDOT2(ra, rr2[2*kp],   Rr0);
            Rr1 = FDOT2(rb, rr2[2*kp+1], Rr1);
            Rz0 = FDOT2(ra, rz2[2*kp],   Rz0);
            Rz1 = FDOT2(rb, rz2[2*kp+1], Rz1);
            Rn0 = FDOT2(ra, rn2[2*kp],   Rn0);
            Rn1 = FDOT2(rb, rn2[2*kp+1], Rn1);
        }
        const float RrB = (Rr0 + Rr1) + bhr, RzB = (Rz0 + Rz1) + bhz;
        const float Rn = Rn0 + Rn1;

        // ---- 16 GRU steps: 4 dynamic groups x 4 unrolled (I-cache OK).
        //      Tokens come from the hoisted regs via cndmask select. ----
#pragma unroll 1
        for (int g = 0; g < 4; ++g) {
            const bool gb1 = (g & 1), gb2 = (g & 2);
            int4 tlo, thi, tg;
            tlo.x = gb1 ? pB.x : pA.x; tlo.y = gb1 ? pB.y : pA.y;
            tlo.z = gb1 ? pB.z : pA.z; tlo.w = gb1 ? pB.w : pA.w;
            thi.x = gb1 ? pD.x : pC.x; thi.y = gb1 ? pD.y : pC.y;
            thi.z = gb1 ? pD.z : pC.z; thi.w = gb1 ? pD.w : pC.w;
            tg.x = gb2 ? thi.x : tlo.x; tg.y = gb2 ? thi.y : tlo.y;
            tg.z = gb2 ? thi.z : tlo.z; tg.w = gb2 ? thi.w : tlo.w;
            const float* GA = G + tg.x*192;
            const float* GB = G + tg.y*192;
            const float* GC = G + tg.z*192;
            const float* GD = G + tg.w*192;
            float gA0 = GA[j], gA1 = GA[64+j], gA2 = GA[128+j];
            float gB0 = GB[j], gB1 = GB[64+j], gB2 = GB[128+j];
            float gC0 = GC[j], gC1 = GC[64+j], gC2 = GC[128+j];
            float gD0 = GD[j], gD1 = GD[64+j], gD2 = GD[128+j];

            GRU_STEP(gA0, gA1, gA2);
            GRU_STEP(gB0, gB1, gB2);
            GRU_STEP(gC0, gC1, gC2);
            GRU_STEP(gD0, gD1, gD2);
        }
    }

    // ---- head: out[b][j] = head_b[j] + sum_k h[k]*head_w[j][k] (fp32) ----
    float o = head_b[j];
#pragma unroll
    for (int k4 = 0; k4 < 16; ++k4) {
        float h0 = rl(h, 4*k4+0), h1 = rl(h, 4*k4+1);
        float h2 = rl(h, 4*k4+2), h3 = rl(h, 4*k4+3);
        const float* hw = head_w + j*64 + 4*k4;
        o += h0*hw[0] + h1*hw[1] + h2*hw[2] + h3*hw[3];
    }
    out[(size_t)b*64 + j] = o;
}

extern "C" void kernel_launch(void* const* d_in, const int* in_sizes, int n_in,
                              void* d_out, int out_size, void* d_ws, size_t ws_size,
                              hipStream_t stream) {
    const int*   seq      = (const int*)  d_in[0];
    const float* memory   = (const float*)d_in[1];
    const float* embed_w  = (const float*)d_in[2];
    const float* w_ih     = (const float*)d_in[3];
    const float* w_hh     = (const float*)d_in[4];
    const float* b_ih     = (const float*)d_in[5];
    const float* b_hh     = (const float*)d_in[6];
    const float* key_w    = (const float*)d_in[7];
    const float* key_b    = (const float*)d_in[8];
    const float* val_w    = (const float*)d_in[9];
    const float* val_b    = (const float*)d_in[10];
    const float* query_w  = (const float*)d_in[11];
    const float* query_b  = (const float*)d_in[12];
    const float* head_w   = (const float*)d_in[13];
    const float* head_b   = (const float*)d_in[14];

    char* ws = (char*)d_ws;
    unsigned* kT2  = (unsigned*)(ws + WS_KT);
    unsigned* vT2  = (unsigned*)(ws + WS_V);
    float*    G    = (float*)   (ws + WS_G);
    unsigned* WPhh2 = (unsigned*)(ws + WS_WPHH);
    unsigned* WR2p  = (unsigned*)(ws + WS_WR);
    unsigned* QP2   = (unsigned*)(ws + WS_QP);
    float4*   KWP   = (float4*)  (ws + WS_KWP);
    float4*   VWP   = (float4*)  (ws + WS_VWP);

    (void)hipFuncSetAttribute((const void*)recurrent_main,
                              hipFuncAttributeMaxDynamicSharedMemorySize,
                              (int)SMEM_BYTES);

    pack_weights<<<64, 256, 0, stream>>>(w_ih, w_hh, query_w, key_w, val_w,
                                         WPhh2, WR2p, QP2, KWP, VWP);
    build_G<<<64, 64, 0, stream>>>(embed_w, w_ih, b_ih, G);
    compute_kv<<<(B_*M_)/4, 256, 0, stream>>>(memory, key_b, val_b, KWP, VWP, kT2, vT2);
    recurrent_main<<<B_, 64, SMEM_BYTES, stream>>>(seq, b_hh, query_b, head_w, head_b,
                                                   kT2, vT2, G, WPhh2, WR2p, QP2,
                                                   (float*)d_out);
}

// Round 8
// 1381.533 us; speedup vs baseline: 1.1778x; 1.0789x over previous
//
#include <hip/hip_runtime.h>
#include <hip/hip_fp16.h>

// FixedFreqModel: B=512, L=2048, M=256, H=64, VOCAB=64, READ_FREQ=16.
// R20 = R17 (1190us steady, best measured) + exactly two minimal edits:
//  1. v-loop: single 128-deep racc chain -> 4 accumulators (the ONLY dot2
//     chain in the kernel with back-to-back dependent accumulates; R19's
//     post-mortem showed the q/R/GRU 3-chain forms were never
//     latency-exposed and splitting them REGRESSED 87us -- reverted).
//  2. packpair -> pkrtz(mine, other): every readlane consumer reads only
//     EVEN lanes' packed values (rl_u(hpu,2k), rl_u(qpu,2t), rl_u(rpu,2k)),
//     so the odd-lane operand swap (2 cndmask/pack) is dead code. Even-lane
//     results bit-identical; ~36 insts/chunk removed from the hot path.
// Everything else byte-identical to R17: q unroll-8 3-chain, scores loop,
// R-matvec 3 chains, 4-group GRU loop with cndmask token select (I-cache
// OK), W_hh + WR register-resident, no pins, no waves_per_eu.

#define B_ 512
#define L_ 2048
#define M_ 256
#define H_ 64
#define C_ 128
#define F_ 16

typedef float v2f __attribute__((ext_vector_type(2)));
typedef _Float16 h2v __attribute__((ext_vector_type(2)));

#if __has_builtin(__builtin_amdgcn_fdot2)
__device__ __forceinline__ float FDOT2(h2v a, h2v b, float c) {
    return __builtin_amdgcn_fdot2(a, b, c, false);
}
#else
__device__ __forceinline__ float FDOT2(h2v a, h2v b, float c) {
    return c + (float)a[0]*(float)b[0] + (float)a[1]*(float)b[1];
}
#endif

__device__ __forceinline__ h2v bch(unsigned u) { return __builtin_bit_cast(h2v, u); }
__device__ __forceinline__ unsigned rl_u(unsigned v, int lane) {
    return (unsigned)__builtin_amdgcn_readlane((int)v, lane);
}
__device__ __forceinline__ float rl(float v, int lane) {
    return __int_as_float(__builtin_amdgcn_readlane(__float_as_int(v), lane));
}
// pack (mine, other) -> half2; consumers only read EVEN lanes, where
// (mine, other) = (h[2t], h[2t+1]) is already the correct order.
__device__ __forceinline__ unsigned pkrtz(float a, float b) {
    auto r = __builtin_amdgcn_cvt_pkrtz(a, b);     // __fp16 ext_vector(2)
    return __builtin_bit_cast(unsigned, r);
}
__device__ __forceinline__ float dot4(float4 a, float4 b) {
    return a.x*b.x + a.y*b.y + a.z*b.z + a.w*b.w;
}
__device__ __forceinline__ float fast_rcp(float x) { return __builtin_amdgcn_rcpf(x); }
__device__ __forceinline__ float sigm(float x) { return fast_rcp(1.f + __expf(-x)); }
__device__ __forceinline__ float tanh_f(float x) {
    float e2 = __expf(-2.f * fabsf(x));
    return copysignf((1.f - e2) * fast_rcp(1.f + e2), x);
}
__device__ __forceinline__ unsigned h2rn(float a, float b) {
    __half2 h = __floats2half2_rn(a, b);
    return __builtin_bit_cast(unsigned, h);
}

// workspace offsets (bytes)
#define WS_KT    0u            // kT2: 512 * 8192 u32 = 16 MB  [b][hh2][m]
#define WS_V     16777216u     // vT2: 512 * 8192 u32 = 16 MB  [b][o][mp]
#define WS_G     33554432u     // 64*192 fp32 = 48 KB
#define WS_WPHH  33603584u     // 6144 u32 = 24 KB  [(k2*3+g)*64+j]
#define WS_WR    33628160u     // 6144 u32 = 24 KB
#define WS_QP    33652736u     // 2048 u32 = 8 KB   [k2*64+j]
#define WS_KWP   33660928u     // 1024 float4 = 16 KB
#define WS_VWP   33677312u     // 16 KB

// dynamic LDS layout (bytes)
#define S_KT   0u        // 32768 : kT2 u32 [hh2=32][m=256]  (uint4 per (hh2, 4m))
#define S_V    32768u    // 33792 : vP u32 [o=64][132] (128 mp-pairs + 4 pad)
#define S_QP   66560u    // 8192  : QP2 u32 [k2=32][j=64]
#define S_P    74752u    // 512   : p fp16 pairs u32 [mp=128]
#define SMEM_BYTES 75264u

// ---------------- pack weights -----------------------------------------------
__global__ void pack_weights(const float* __restrict__ w_ih,
                             const float* __restrict__ w_hh,
                             const float* __restrict__ qw,
                             const float* __restrict__ kw,
                             const float* __restrict__ vw,
                             unsigned* __restrict__ WPhh2,
                             unsigned* __restrict__ WR2p,
                             unsigned* __restrict__ QP2,
                             float4* __restrict__ KWP,
                             float4* __restrict__ VWP)
{
    int idx = blockIdx.x * 256 + threadIdx.x;
    if (idx < 6144) {                        // WPhh2[(k2*3+g)*64+j]
        int j = idx & 63, t = idx >> 6, g = t % 3, k2 = t / 3;
        const float* s = w_hh + (g*64 + j)*64 + 2*k2;
        WPhh2[idx] = h2rn(s[0], s[1]);
    } else if (idx < 12288) {                // WR2p: retrieved half of w_ih
        int i = idx - 6144;
        int j = i & 63, t = i >> 6, g = t % 3, k2 = t / 3;
        const float* s = w_ih + (g*64 + j)*128 + 64 + 2*k2;
        WR2p[i] = h2rn(s[0], s[1]);
    } else if (idx < 14336) {                // QP2[k2*64+j]
        int i = idx - 12288;
        int j = i & 63, k2 = i >> 6;
        const float* s = qw + j*64 + 2*k2;
        QP2[i] = h2rn(s[0], s[1]);
    } else if (idx < 15360) {
        int i = idx - 14336;
        int j = i & 63, k4 = i >> 6;
        const float* s = kw + j*64 + 4*k4;
        KWP[i] = make_float4(s[0], s[1], s[2], s[3]);
    } else if (idx < 16384) {
        int i = idx - 15360;
        int j = i & 63, k4 = i >> 6;
        const float* s = vw + j*64 + 4*k4;
        VWP[i] = make_float4(s[0], s[1], s[2], s[3]);
    }
}

// ---------------- G[v][o] = sum_k embed[v][k]*w_ih[o][k] + b_ih[o] ----------
__global__ __launch_bounds__(64) void build_G(const float* __restrict__ embed_w,
                                              const float* __restrict__ w_ih,
                                              const float* __restrict__ b_ih,
                                              float* __restrict__ G)
{
    int v = blockIdx.x, j = threadIdx.x;
    __shared__ float e_s[64];
    e_s[j] = embed_w[v*64 + j];
    __syncthreads();
    float a0 = b_ih[j], a1 = b_ih[64 + j], a2 = b_ih[128 + j];
    for (int k = 0; k < 64; ++k) {
        float e = e_s[k];
        a0 += e * w_ih[j*128 + k];
        a1 += e * w_ih[(64 + j)*128 + k];
        a2 += e * w_ih[(128 + j)*128 + k];
    }
    G[v*192 + j]       = a0;
    G[v*192 + 64 + j]  = a1;
    G[v*192 + 128 + j] = a2;
}

// ------- k/v precompute (kT hh-pair u32; v m-pair-transposed u32) ------------
__global__ __launch_bounds__(256) void compute_kv(const float* __restrict__ memory,
                                                  const float* __restrict__ key_b,
                                                  const float* __restrict__ val_b,
                                                  const float4* __restrict__ KWP,
                                                  const float4* __restrict__ VWP,
                                                  unsigned* __restrict__ kT2,
                                                  unsigned* __restrict__ vT2)
{
    int wid = threadIdx.x >> 6;
    int o   = threadIdx.x & 63;
    int row = blockIdx.x * 4 + wid;          // row = b*256 + m
    int b = row >> 8, m = row & 255;
    __shared__ __align__(16) float mem_s[4][64];
    __shared__ float avs[4][64];
    mem_s[wid][o] = memory[(size_t)row * 64 + o];
    __syncthreads();
    float ak = key_b[o], av = val_b[o];
    const float4* m4 = (const float4*)mem_s[wid];
#pragma unroll
    for (int k4 = 0; k4 < 16; ++k4) {
        float4 mm = m4[k4];
        ak += dot4(mm, KWP[k4*64 + o]);
        av += dot4(mm, VWP[k4*64 + o]);
    }
    float nb = __shfl_xor(ak, 1);            // k[o^1][m]
    if ((o & 1) == 0)                        // pair (k[o][m], k[o+1][m])
        kT2[((size_t)b*32 + (o >> 1))*256 + m] = h2rn(ak, nb);
    avs[wid][o] = av;
    __syncthreads();
    if ((wid & 1) == 0) {                    // pair (v[m][o], v[m+1][o]), m even
        vT2[((size_t)b*64 + o)*128 + (m >> 1)] = h2rn(avs[wid][o], avs[wid+1][o]);
    }
}

// one GRU step: h broadcast as half2 via readlane; dot2 matvec; no LDS
#define GRU_STEP(cg0, cg1, cg2) do {                                        \
    float gr = (cg0) + RrB, gz = (cg1) + RzB, gn = bhn;                     \
    _Pragma("unroll")                                                       \
    for (int kp = 0; kp < 32; ++kp) {                                       \
        h2v hhp = bch(rl_u(hpu, 2*kp));                                     \
        gr = FDOT2(hhp, wr2[kp], gr);                                       \
        gz = FDOT2(hhp, wz2[kp], gz);                                       \
        gn = FDOT2(hhp, wn2[kp], gn);                                       \
    }                                                                       \
    float r_ = sigm(gr);                                                    \
    float z_ = sigm(gz);                                                    \
    float n_ = tanh_f(((cg2) + Rn) + r_ * gn);                              \
    h = fmaf(z_, h - n_, n_);                                               \
    float hx_ = __shfl_xor(h, 1);                                           \
    hpu = pkrtz(h, hx_);                                                    \
} while (0)

// ---------------- main recurrent kernel: 1 wave per batch element ------------
__global__ __launch_bounds__(64, 1) void recurrent_main(
    const int*   __restrict__ seq,
    const float* __restrict__ b_hh,
    const float* __restrict__ query_b,
    const float* __restrict__ head_w,
    const float* __restrict__ head_b,
    const unsigned* __restrict__ kT2g,
    const unsigned* __restrict__ vT2g,
    const float* __restrict__ G,
    const unsigned* __restrict__ WPhh2,
    const unsigned* __restrict__ WR2p,
    const unsigned* __restrict__ QP2g,
    float* __restrict__ out)
{
    const int b = blockIdx.x;
    const int j = threadIdx.x;

    extern __shared__ __align__(16) char smem[];
    const uint4* kT2_lds = (const uint4*)(smem + S_KT);  // [hh2*64 + j]: 4 m-pairs
    const unsigned* qp2  = (const unsigned*)(smem + S_QP); // [k2*64 + j]

    // ---- stage kT2, vT2 (repad 128->132 u32 rows), QP2 into LDS once ----
    {
        const uint4* kTg = (const uint4*)(kT2g + (size_t)b * 8192);
        uint4* kTls = (uint4*)(smem + S_KT);
#pragma unroll
        for (int i = 0; i < 32; ++i) kTls[i*64 + j] = kTg[i*64 + j];
        const uint4* vg4 = (const uint4*)(vT2g + (size_t)b * 8192);
        uint4* vls4 = (uint4*)(smem + S_V);
#pragma unroll
        for (int i = 0; i < 32; ++i) {
            int t = i*64 + j;                 // global quad: o = t>>5, q = t&31
            vls4[(t >> 5)*33 + (t & 31)] = vg4[t];
        }
        const uint4* qpg = (const uint4*)QP2g;
        uint4* qls = (uint4*)(smem + S_QP);
#pragma unroll
        for (int i = 0; i < 8; ++i) qls[i*64 + j] = qpg[i*64 + j];
    }

    // ---- W_hh in registers as half2: 96 words (compiler parks in AGPRs) ----
    h2v wr2[32], wz2[32], wn2[32];
#pragma unroll
    for (int k2 = 0; k2 < 32; ++k2) {
        wr2[k2] = bch(WPhh2[(k2*3 + 0)*64 + j]);
        wz2[k2] = bch(WPhh2[(k2*3 + 1)*64 + j]);
        wn2[k2] = bch(WPhh2[(k2*3 + 2)*64 + j]);
    }
    // ---- WR (retrieved-half of w_ih) likewise: 96 words, loaded ONCE ----
    h2v rr2[32], rz2[32], rn2[32];
#pragma unroll
    for (int k2 = 0; k2 < 32; ++k2) {
        rr2[k2] = bch(WR2p[(k2*3 + 0)*64 + j]);
        rz2[k2] = bch(WR2p[(k2*3 + 1)*64 + j]);
        rn2[k2] = bch(WR2p[(k2*3 + 2)*64 + j]);
    }

    float h = 0.f;                       // lane j owns h[j]; never leaves regs
    unsigned hpu = 0u;                   // packed (h[2t], h[2t+1]) fp16 pair
    const float bhr = b_hh[j], bhz = b_hh[64 + j], bhn = b_hh[128 + j];
    const float qb  = query_b[j];

    const int* seqb = seq + (size_t)b * L_;
    const uint4* vrow = (const uint4*)(smem + S_V) + j*33;   // lane's o-row
    const uint4* p4   = (const uint4*)(smem + S_P);
    __builtin_amdgcn_wave_barrier();

    for (int c = 0; c < C_; ++c) {
        const int c16 = c * F_;

        // ---- token hoist: all 4 group int4s issued at chunk top ----
        const int4 pA = *(const int4*)(seqb + c16);
        const int4 pB = *(const int4*)(seqb + c16 + 4);
        const int4 pC = *(const int4*)(seqb + c16 + 8);
        const int4 pD = *(const int4*)(seqb + c16 + 12);

        // ---- q[j] = qb + sum_k h[k]*Wq[j][k]  (dot2: h pairs + QP2 LDS) ----
        float q = qb;
#pragma unroll 8
        for (int k2 = 0; k2 < 32; ++k2) {
            h2v pp = bch(qp2[k2*64 + j]);
            h2v hh = bch(rl_u(hpu, 2*k2));
            q = FDOT2(hh, pp, q);
        }

        // ---- scores: lane j owns m = 4j..4j+3 (dot2 over hh-pairs) ----
        float qx = __shfl_xor(q, 1);
        unsigned qpu = pkrtz(q, qx);
        float s0 = 0.f, s1 = 0.f, s2 = 0.f, s3 = 0.f;
#pragma unroll 8
        for (int t = 0; t < 32; ++t) {
            h2v qq = bch(rl_u(qpu, 2*t));
            uint4 kk = kT2_lds[t*64 + j];
            s0 = FDOT2(bch(kk.x), qq, s0);
            s1 = FDOT2(bch(kk.y), qq, s1);
            s2 = FDOT2(bch(kk.z), qq, s2);
            s3 = FDOT2(bch(kk.w), qq, s3);
        }
        const float scale = 0.125f;
        // softmax, no max-sub (|s| small), rcp not div
        float4 p;
        p.x = __expf(s0*scale); p.y = __expf(s1*scale);
        p.z = __expf(s2*scale); p.w = __expf(s3*scale);
        float sum = (p.x + p.y) + (p.z + p.w);
#pragma unroll
        for (int o = 32; o > 0; o >>= 1) sum += __shfl_xor(sum, o);
        float inv = fast_rcp(sum);
        // p as fp16 pairs (unnormalized): mp=2j -> (p[4j],p[4j+1]); 2j+1 -> ...
        *(uint2*)(smem + S_P + (size_t)j*8) =
            make_uint2(pkrtz(p.x, p.y), pkrtz(p.z, p.w));
        __builtin_amdgcn_wave_barrier();

        // ---- retrieved: lane j owns ret[j]; 4 accs (chain depth 32) ----
        float r0 = 0.f, r1 = 0.f, r2 = 0.f, r3 = 0.f;
#pragma unroll 8
        for (int qd = 0; qd < 32; ++qd) {
            uint4 vv = vrow[qd];          // pairs mp = 4qd..4qd+3 for o=j
            uint4 pp = p4[qd];            // broadcast
            r0 = FDOT2(bch(pp.x), bch(vv.x), r0);
            r1 = FDOT2(bch(pp.y), bch(vv.y), r1);
            r2 = FDOT2(bch(pp.z), bch(vv.z), r2);
            r3 = FDOT2(bch(pp.w), bch(vv.w), r3);
        }
        float ret = ((r0 + r1) + (r2 + r3)) * inv;

        // ---- R matvec: ret packed like h (pairs via shfl); WR in regs ----
        float rx = __shfl_xor(ret, 1);
        unsigned rpu = pkrtz(ret, rx);
        float Rr = 0.f, Rz = 0.f, Rn = 0.f;
#pragma unroll
        for (int k2 = 0; k2 < 32; ++k2) {
            h2v rr = bch(rl_u(rpu, 2*k2));
            Rr = FDOT2(rr, rr2[k2], Rr);
            Rz = FDOT2(rr, rz2[k2], Rz);
            Rn = FDOT2(rr, rn2[k2], Rn);
        }
        const float RrB = Rr + bhr, RzB = Rz + bhz;

        // ---- 16 GRU steps: 4 dynamic groups x 4 unrolled (I-cache OK).
        //      Tokens come from the hoisted regs via cndmask select. ----
#pragma unroll 1
        for (int g = 0; g < 4; ++g) {
            const bool gb1 = (g & 1), gb2 = (g & 2);
            int4 tlo, thi, tg;
            tlo.x = gb1 ? pB.x : pA.x; tlo.y = gb1 ? pB.y : pA.y;
            tlo.z = gb1 ? pB.z : pA.z; tlo.w = gb1 ? pB.w : pA.w;
            thi.x = gb1 ? pD.x : pC.x; thi.y = gb1 ? pD.y : pC.y;
            thi.z = gb1 ? pD.z : pC.z; thi.w = gb1 ? pD.w : pC.w;
            tg.x = gb2 ? thi.x : tlo.x; tg.y = gb2 ? thi.y : tlo.y;
            tg.z = gb2 ? thi.z : tlo.z; tg.w = gb2 ? thi.w : tlo.w;
            const float* GA = G + tg.x*192;
            const float* GB = G + tg.y*192;
            const float* GC = G + tg.z*192;
            const float* GD = G + tg.w*192;
            float gA0 = GA[j], gA1 = GA[64+j], gA2 = GA[128+j];
            float gB0 = GB[j], gB1 = GB[64+j], gB2 = GB[128+j];
            float gC0 = GC[j], gC1 = GC[64+j], gC2 = GC[128+j];
            float gD0 = GD[j], gD1 = GD[64+j], gD2 = GD[128+j];

            GRU_STEP(gA0, gA1, gA2);
            GRU_STEP(gB0, gB1, gB2);
            GRU_STEP(gC0, gC1, gC2);
            GRU_STEP(gD0, gD1, gD2);
        }
    }

    // ---- head: out[b][j] = head_b[j] + sum_k h[k]*head_w[j][k] (fp32) ----
    float o = head_b[j];
#pragma unroll
    for (int k4 = 0; k4 < 16; ++k4) {
        float h0 = rl(h, 4*k4+0), h1 = rl(h, 4*k4+1);
        float h2 = rl(h, 4*k4+2), h3 = rl(h, 4*k4+3);
        const float* hw = head_w + j*64 + 4*k4;
        o += h0*hw[0] + h1*hw[1] + h2*hw[2] + h3*hw[3];
    }
    out[(size_t)b*64 + j] = o;
}

extern "C" void kernel_launch(void* const* d_in, const int* in_sizes, int n_in,
                              void* d_out, int out_size, void* d_ws, size_t ws_size,
                              hipStream_t stream) {
    const int*   seq      = (const int*)  d_in[0];
    const float* memory   = (const float*)d_in[1];
    const float* embed_w  = (const float*)d_in[2];
    const float* w_ih     = (const float*)d_in[3];
    const float* w_hh     = (const float*)d_in[4];
    const float* b_ih     = (const float*)d_in[5];
    const float* b_hh     = (const float*)d_in[6];
    const float* key_w    = (const float*)d_in[7];
    const float* key_b    = (const float*)d_in[8];
    const float* val_w    = (const float*)d_in[9];
    const float* val_b    = (const float*)d_in[10];
    const float* query_w  = (const float*)d_in[11];
    const float* query_b  = (const float*)d_in[12];
    const float* head_w   = (const float*)d_in[13];
    const float* head_b   = (const float*)d_in[14];

    char* ws = (char*)d_ws;
    unsigned* kT2  = (unsigned*)(ws + WS_KT);
    unsigned* vT2  = (unsigned*)(ws + WS_V);
    float*    G    = (float*)   (ws + WS_G);
    unsigned* WPhh2 = (unsigned*)(ws + WS_WPHH);
    unsigned* WR2p  = (unsigned*)(ws + WS_WR);
    unsigned* QP2   = (unsigned*)(ws + WS_QP);
    float4*   KWP   = (float4*)  (ws + WS_KWP);
    float4*   VWP   = (float4*)  (ws + WS_VWP);

    (void)hipFuncSetAttribute((const void*)recurrent_main,
                              hipFuncAttributeMaxDynamicSharedMemorySize,
                              (int)SMEM_BYTES);

    pack_weights<<<64, 256, 0, stream>>>(w_ih, w_hh, query_w, key_w, val_w,
                                         WPhh2, WR2p, QP2, KWP, VWP);
    build_G<<<64, 64, 0, stream>>>(embed_w, w_ih, b_ih, G);
    compute_kv<<<(B_*M_)/4, 256, 0, stream>>>(memory, key_b, val_b, KWP, VWP, kT2, vT2);
    recurrent_main<<<B_, 64, SMEM_BYTES, stream>>>(seq, b_hh, query_b, head_w, head_b,
                                                   kT2, vT2, G, WPhh2, WR2p, QP2,
                                                   (float*)d_out);
}

// Round 9
// 1323.334 us; speedup vs baseline: 1.2296x; 1.0440x over previous
//
#include <hip/hip_runtime.h>
#include <hip/hip_fp16.h>

// FixedFreqModel: B=512, L=2048, M=256, H=64, VOCAB=64, READ_FREQ=16.
// R21 = R20 (1156us steady, best) + two serial-latency removals:
//  1. KQ-fold: s_m = k_m.(Wq h + qb) = K'_m.h + c_m with K' = k.Wq and
//     c_m = k_m.qb. Folded at the WEIGHT level: K' = mem.(Kw^T Wq) + kb.Wq,
//     so compute_kv produces K' pairs at IDENTICAL cost (KQ 64x64 computed
//     once by fold_kq/pack_kq). The entire q-matvec phase (~96 insts +
//     ~300cy serial chain + pack) vanishes from the recurrent loop; scores
//     consume hpu (packed h pairs) directly, init from c (fp32, in regs).
//  2. Late-add G: GRU gate init gr=RrB (not cg0+RrB); cg0/cg1 added at the
//     tail (sigm(gr+cg0)). The 12 G loads per group are now first consumed
//     AFTER the ~256cy matvec instead of by its first instruction -- their
//     L1/L2 latency is covered. fp32 reassociation only (compiler cannot do
//     this itself). This attacks what R14 (rotation copies) and R18
//     (I-cache blowup) failed at, with zero structural change.
// Everything else byte-identical to R20: scores/v/R loops, 4-group GRU with
// cndmask token select, W_hh + WR register-resident, no pins.

#define B_ 512
#define L_ 2048
#define M_ 256
#define H_ 64
#define C_ 128
#define F_ 16

typedef float v2f __attribute__((ext_vector_type(2)));
typedef _Float16 h2v __attribute__((ext_vector_type(2)));

#if __has_builtin(__builtin_amdgcn_fdot2)
__device__ __forceinline__ float FDOT2(h2v a, h2v b, float c) {
    return __builtin_amdgcn_fdot2(a, b, c, false);
}
#else
__device__ __forceinline__ float FDOT2(h2v a, h2v b, float c) {
    return c + (float)a[0]*(float)b[0] + (float)a[1]*(float)b[1];
}
#endif

__device__ __forceinline__ h2v bch(unsigned u) { return __builtin_bit_cast(h2v, u); }
__device__ __forceinline__ unsigned rl_u(unsigned v, int lane) {
    return (unsigned)__builtin_amdgcn_readlane((int)v, lane);
}
__device__ __forceinline__ float rl(float v, int lane) {
    return __int_as_float(__builtin_amdgcn_readlane(__float_as_int(v), lane));
}
__device__ __forceinline__ unsigned pkrtz(float a, float b) {
    auto r = __builtin_amdgcn_cvt_pkrtz(a, b);     // __fp16 ext_vector(2)
    return __builtin_bit_cast(unsigned, r);
}
__device__ __forceinline__ float dot4(float4 a, float4 b) {
    return a.x*b.x + a.y*b.y + a.z*b.z + a.w*b.w;
}
__device__ __forceinline__ float fast_rcp(float x) { return __builtin_amdgcn_rcpf(x); }
__device__ __forceinline__ float sigm(float x) { return fast_rcp(1.f + __expf(-x)); }
__device__ __forceinline__ float tanh_f(float x) {
    float e2 = __expf(-2.f * fabsf(x));
    return copysignf((1.f - e2) * fast_rcp(1.f + e2), x);
}
__device__ __forceinline__ unsigned h2rn(float a, float b) {
    __half2 h = __floats2half2_rn(a, b);
    return __builtin_bit_cast(unsigned, h);
}

// workspace offsets (bytes)
#define WS_KT    0u            // K'T2: 512 * 8192 u32 = 16 MB  [b][hh2][m]
#define WS_V     16777216u     // vT2: 512 * 8192 u32 = 16 MB  [b][o][mp]
#define WS_G     33554432u     // 64*192 fp32 = 48 KB
#define WS_WPHH  33603584u     // 6144 u32 = 24 KB  [(k2*3+g)*64+j]
#define WS_WR    33628160u     // 6144 u32 = 24 KB
#define WS_QP    33652736u     // 2048 u32 = 8 KB (unused since R21)
#define WS_KWP   33660928u     // 1024 float4 = 16 KB -> KQP (folded K.Q)
#define WS_VWP   33677312u     // 16 KB
#define WS_KQF   33693696u     // 4096 fp32 = 16 KB (KQ scalar, pre-pack)
#define WS_BQ    33710080u     // 64 fp32 (bq = kb.Wq)
#define WS_KQV   33710336u     // 64 fp32 (kq = Kw^T qb)
#define WS_C0    33710592u     // 1 fp32 (c0 = kb.qb), padded
#define WS_CB    33710848u     // 512*256 fp32 = 512 KB (c[b][m])

// dynamic LDS layout (bytes)
#define S_KT   0u        // 32768 : K'T2 u32 [hh2=32][m=256]
#define S_V    32768u    // 33792 : vP u32 [o=64][132] (128 mp-pairs + 4 pad)
#define S_P    66560u    // 512   : p fp16 pairs u32 [mp=128]
#define SMEM_BYTES 67072u

// ---------------- pack weights -----------------------------------------------
__global__ void pack_weights(const float* __restrict__ w_ih,
                             const float* __restrict__ w_hh,
                             const float* __restrict__ vw,
                             unsigned* __restrict__ WPhh2,
                             unsigned* __restrict__ WR2p,
                             float4* __restrict__ VWP)
{
    int idx = blockIdx.x * 256 + threadIdx.x;
    if (idx < 6144) {                        // WPhh2[(k2*3+g)*64+j]
        int j = idx & 63, t = idx >> 6, g = t % 3, k2 = t / 3;
        const float* s = w_hh + (g*64 + j)*64 + 2*k2;
        WPhh2[idx] = h2rn(s[0], s[1]);
    } else if (idx < 12288) {                // WR2p: retrieved half of w_ih
        int i = idx - 6144;
        int j = i & 63, t = i >> 6, g = t % 3, k2 = t / 3;
        const float* s = w_ih + (g*64 + j)*128 + 64 + 2*k2;
        WR2p[i] = h2rn(s[0], s[1]);
    } else if (idx < 13312) {                // VWP
        int i = idx - 12288;
        int j = i & 63, k4 = i >> 6;
        const float* s = vw + j*64 + 4*k4;
        VWP[i] = make_float4(s[0], s[1], s[2], s[3]);
    }
}

// ------ fold_kq: KQ[d][j] = sum_t Kw[t][d]*Wq[t][j]; bq, kq, c0 --------------
__global__ __launch_bounds__(64) void fold_kq(const float* __restrict__ kw,
                                              const float* __restrict__ qw,
                                              const float* __restrict__ kb,
                                              const float* __restrict__ qb,
                                              float* __restrict__ KQf,
                                              float* __restrict__ bqv,
                                              float* __restrict__ kqv,
                                              float* __restrict__ c0p)
{
    int d = blockIdx.x, j = threadIdx.x;
    __shared__ float kcol[64], kbs[64], qbs[64];
    kcol[j] = kw[j*64 + d];
    kbs[j]  = kb[j];
    qbs[j]  = qb[j];
    __syncthreads();
    float acc = 0.f, accq = 0.f;
    for (int t = 0; t < 64; ++t) {
        float kc = kcol[t];
        acc  += kc * qw[t*64 + j];
        accq += kc * qbs[t];
    }
    KQf[d*64 + j] = acc;
    if (j == 0) kqv[d] = accq;
    if (d == 0) {
        float vb = 0.f;
        for (int t = 0; t < 64; ++t) vb += kbs[t] * qw[t*64 + j];
        bqv[j] = vb;
        if (j == 0) {
            float c0 = 0.f;
            for (int t = 0; t < 64; ++t) c0 += kbs[t] * qbs[t];
            *c0p = c0;
        }
    }
}

// ------ pack_kq: KQP[k4*64+o] = (KQ[4k4+0..3][o]) for dot4 -------------------
__global__ __launch_bounds__(256) void pack_kq(const float* __restrict__ KQf,
                                               float4* __restrict__ KQP)
{
    int i = blockIdx.x * 256 + threadIdx.x;
    if (i < 1024) {
        int o = i & 63, k4 = i >> 6;
        KQP[i] = make_float4(KQf[(4*k4+0)*64 + o], KQf[(4*k4+1)*64 + o],
                             KQf[(4*k4+2)*64 + o], KQf[(4*k4+3)*64 + o]);
    }
}

// ---------------- G[v][o] = sum_k embed[v][k]*w_ih[o][k] + b_ih[o] ----------
__global__ __launch_bounds__(64) void build_G(const float* __restrict__ embed_w,
                                              const float* __restrict__ w_ih,
                                              const float* __restrict__ b_ih,
                                              float* __restrict__ G)
{
    int v = blockIdx.x, j = threadIdx.x;
    __shared__ float e_s[64];
    e_s[j] = embed_w[v*64 + j];
    __syncthreads();
    float a0 = b_ih[j], a1 = b_ih[64 + j], a2 = b_ih[128 + j];
    for (int k = 0; k < 64; ++k) {
        float e = e_s[k];
        a0 += e * w_ih[j*128 + k];
        a1 += e * w_ih[(64 + j)*128 + k];
        a2 += e * w_ih[(128 + j)*128 + k];
    }
    G[v*192 + j]       = a0;
    G[v*192 + 64 + j]  = a1;
    G[v*192 + 128 + j] = a2;
}

// ------- k/v precompute: K' (folded) pairs; v m-pair-transposed; c[b][m] -----
__global__ __launch_bounds__(256) void compute_kv(const float* __restrict__ memory,
                                                  const float* __restrict__ bqv,
                                                  const float* __restrict__ val_b,
                                                  const float4* __restrict__ KQP,
                                                  const float4* __restrict__ VWP,
                                                  const float* __restrict__ kqv,
                                                  const float* __restrict__ c0p,
                                                  unsigned* __restrict__ kT2,
                                                  unsigned* __restrict__ vT2,
                                                  float* __restrict__ cB)
{
    int wid = threadIdx.x >> 6;
    int o   = threadIdx.x & 63;
    int row = blockIdx.x * 4 + wid;          // row = b*256 + m
    int b = row >> 8, m = row & 255;
    __shared__ __align__(16) float mem_s[4][64];
    __shared__ float avs[4][64];
    mem_s[wid][o] = memory[(size_t)row * 64 + o];
    __syncthreads();
    float ak = bqv[o], av = val_b[o], ac = *c0p;
    const float4* m4  = (const float4*)mem_s[wid];
    const float4* kq4 = (const float4*)kqv;
#pragma unroll
    for (int k4 = 0; k4 < 16; ++k4) {
        float4 mm = m4[k4];
        ak += dot4(mm, KQP[k4*64 + o]);
        av += dot4(mm, VWP[k4*64 + o]);
        ac += dot4(mm, kq4[k4]);
    }
    float nb = __shfl_xor(ak, 1);            // K'[o^1][m]
    if ((o & 1) == 0)                        // pair (K'[o][m], K'[o+1][m])
        kT2[((size_t)b*32 + (o >> 1))*256 + m] = h2rn(ak, nb);
    avs[wid][o] = av;
    if (o == 0) cB[row] = ac;
    __syncthreads();
    if ((wid & 1) == 0) {                    // pair (v[m][o], v[m+1][o]), m even
        vT2[((size_t)b*64 + o)*128 + (m >> 1)] = h2rn(avs[wid][o], avs[wid+1][o]);
    }
}

// one GRU step: h broadcast as half2 via readlane; dot2 matvec; no LDS.
// G values (cg0/cg1) consumed at the TAIL so their load latency hides
// under the ~256cy matvec (fp32 reassociation only).
#define GRU_STEP(cg0, cg1, cg2) do {                                        \
    float gr = RrB, gz = RzB, gn = bhn;                                     \
    _Pragma("unroll")                                                       \
    for (int kp = 0; kp < 32; ++kp) {                                       \
        h2v hhp = bch(rl_u(hpu, 2*kp));                                     \
        gr = FDOT2(hhp, wr2[kp], gr);                                       \
        gz = FDOT2(hhp, wz2[kp], gz);                                       \
        gn = FDOT2(hhp, wn2[kp], gn);                                       \
    }                                                                       \
    float r_ = sigm(gr + (cg0));                                            \
    float z_ = sigm(gz + (cg1));                                            \
    float n_ = tanh_f(((cg2) + Rn) + r_ * gn);                              \
    h = fmaf(z_, h - n_, n_);                                               \
    float hx_ = __shfl_xor(h, 1);                                           \
    hpu = pkrtz(h, hx_);                                                    \
} while (0)

// ---------------- main recurrent kernel: 1 wave per batch element ------------
__global__ __launch_bounds__(64, 1) void recurrent_main(
    const int*   __restrict__ seq,
    const float* __restrict__ b_hh,
    const float* __restrict__ head_w,
    const float* __restrict__ head_b,
    const unsigned* __restrict__ kT2g,
    const unsigned* __restrict__ vT2g,
    const float* __restrict__ G,
    const unsigned* __restrict__ WPhh2,
    const unsigned* __restrict__ WR2p,
    const float* __restrict__ cB,
    float* __restrict__ out)
{
    const int b = blockIdx.x;
    const int j = threadIdx.x;

    extern __shared__ __align__(16) char smem[];
    const uint4* kT2_lds = (const uint4*)(smem + S_KT);  // [hh2*64 + j]: 4 m-pairs

    // ---- stage K'T2, vT2 (repad 128->132 u32 rows) into LDS once ----
    {
        const uint4* kTg = (const uint4*)(kT2g + (size_t)b * 8192);
        uint4* kTls = (uint4*)(smem + S_KT);
#pragma unroll
        for (int i = 0; i < 32; ++i) kTls[i*64 + j] = kTg[i*64 + j];
        const uint4* vg4 = (const uint4*)(vT2g + (size_t)b * 8192);
        uint4* vls4 = (uint4*)(smem + S_V);
#pragma unroll
        for (int i = 0; i < 32; ++i) {
            int t = i*64 + j;                 // global quad: o = t>>5, q = t&31
            vls4[(t >> 5)*33 + (t & 31)] = vg4[t];
        }
    }

    // ---- W_hh in registers as half2: 96 words (compiler parks in AGPRs) ----
    h2v wr2[32], wz2[32], wn2[32];
#pragma unroll
    for (int k2 = 0; k2 < 32; ++k2) {
        wr2[k2] = bch(WPhh2[(k2*3 + 0)*64 + j]);
        wz2[k2] = bch(WPhh2[(k2*3 + 1)*64 + j]);
        wn2[k2] = bch(WPhh2[(k2*3 + 2)*64 + j]);
    }
    // ---- WR (retrieved-half of w_ih) likewise: 96 words, loaded ONCE ----
    h2v rr2[32], rz2[32], rn2[32];
#pragma unroll
    for (int k2 = 0; k2 < 32; ++k2) {
        rr2[k2] = bch(WR2p[(k2*3 + 0)*64 + j]);
        rz2[k2] = bch(WR2p[(k2*3 + 1)*64 + j]);
        rn2[k2] = bch(WR2p[(k2*3 + 2)*64 + j]);
    }

    float h = 0.f;                       // lane j owns h[j]; never leaves regs
    unsigned hpu = 0u;                   // packed (h[2t], h[2t+1]) fp16 pair
    const float bhr = b_hh[j], bhz = b_hh[64 + j], bhn = b_hh[128 + j];
    // scores bias: c[b][m] for lane's m = 4j..4j+3 (fp32, in regs all session)
    const float4 cc = *(const float4*)(cB + (size_t)b*256 + 4*j);

    const int* seqb = seq + (size_t)b * L_;
    const uint4* vrow = (const uint4*)(smem + S_V) + j*33;   // lane's o-row
    const uint4* p4   = (const uint4*)(smem + S_P);
    __builtin_amdgcn_wave_barrier();

    for (int c = 0; c < C_; ++c) {
        const int c16 = c * F_;

        // ---- token hoist: all 4 group int4s issued at chunk top ----
        const int4 pA = *(const int4*)(seqb + c16);
        const int4 pB = *(const int4*)(seqb + c16 + 4);
        const int4 pC = *(const int4*)(seqb + c16 + 8);
        const int4 pD = *(const int4*)(seqb + c16 + 12);

        // ---- scores directly from h pairs (q folded into K'): lane j owns
        //      m = 4j..4j+3; s init = c[m] ----
        float s0 = cc.x, s1 = cc.y, s2 = cc.z, s3 = cc.w;
#pragma unroll 8
        for (int t = 0; t < 32; ++t) {
            h2v qq = bch(rl_u(hpu, 2*t));
            uint4 kk = kT2_lds[t*64 + j];
            s0 = FDOT2(bch(kk.x), qq, s0);
            s1 = FDOT2(bch(kk.y), qq, s1);
            s2 = FDOT2(bch(kk.z), qq, s2);
            s3 = FDOT2(bch(kk.w), qq, s3);
        }
        const float scale = 0.125f;
        // softmax, no max-sub (|s| small), rcp not div
        float4 p;
        p.x = __expf(s0*scale); p.y = __expf(s1*scale);
        p.z = __expf(s2*scale); p.w = __expf(s3*scale);
        float sum = (p.x + p.y) + (p.z + p.w);
#pragma unroll
        for (int o = 32; o > 0; o >>= 1) sum += __shfl_xor(sum, o);
        float inv = fast_rcp(sum);
        // p as fp16 pairs (unnormalized): mp=2j -> (p[4j],p[4j+1]); 2j+1 -> ...
        *(uint2*)(smem + S_P + (size_t)j*8) =
            make_uint2(pkrtz(p.x, p.y), pkrtz(p.z, p.w));
        __builtin_amdgcn_wave_barrier();

        // ---- retrieved: lane j owns ret[j]; 4 accs (chain depth 32) ----
        float r0 = 0.f, r1 = 0.f, r2 = 0.f, r3 = 0.f;
#pragma unroll 8
        for (int qd = 0; qd < 32; ++qd) {
            uint4 vv = vrow[qd];          // pairs mp = 4qd..4qd+3 for o=j
            uint4 pp = p4[qd];            // broadcast
            r0 = FDOT2(bch(pp.x), bch(vv.x), r0);
            r1 = FDOT2(bch(pp.y), bch(vv.y), r1);
            r2 = FDOT2(bch(pp.z), bch(vv.z), r2);
            r3 = FDOT2(bch(pp.w), bch(vv.w), r3);
        }
        float ret = ((r0 + r1) + (r2 + r3)) * inv;

        // ---- R matvec: ret packed like h (pairs via shfl); WR in regs ----
        float rx = __shfl_xor(ret, 1);
        unsigned rpu = pkrtz(ret, rx);
        float Rr = 0.f, Rz = 0.f, Rn = 0.f;
#pragma unroll
        for (int k2 = 0; k2 < 32; ++k2) {
            h2v rr = bch(rl_u(rpu, 2*k2));
            Rr = FDOT2(rr, rr2[k2], Rr);
            Rz = FDOT2(rr, rz2[k2], Rz);
            Rn = FDOT2(rr, rn2[k2], Rn);
        }
        const float RrB = Rr + bhr, RzB = Rz + bhz;

        // ---- 16 GRU steps: 4 dynamic groups x 4 unrolled (I-cache OK).
        //      Tokens from hoisted regs via cndmask; G loads issued at group
        //      top, consumed at step tails (late-add). ----
#pragma unroll 1
        for (int g = 0; g < 4; ++g) {
            const bool gb1 = (g & 1), gb2 = (g & 2);
            int4 tlo, thi, tg;
            tlo.x = gb1 ? pB.x : pA.x; tlo.y = gb1 ? pB.y : pA.y;
            tlo.z = gb1 ? pB.z : pA.z; tlo.w = gb1 ? pB.w : pA.w;
            thi.x = gb1 ? pD.x : pC.x; thi.y = gb1 ? pD.y : pC.y;
            thi.z = gb1 ? pD.z : pC.z; thi.w = gb1 ? pD.w : pC.w;
            tg.x = gb2 ? thi.x : tlo.x; tg.y = gb2 ? thi.y : tlo.y;
            tg.z = gb2 ? thi.z : tlo.z; tg.w = gb2 ? thi.w : tlo.w;
            const float* GA = G + tg.x*192;
            const float* GB = G + tg.y*192;
            const float* GC = G + tg.z*192;
            const float* GD = G + tg.w*192;
            float gA0 = GA[j], gA1 = GA[64+j], gA2 = GA[128+j];
            float gB0 = GB[j], gB1 = GB[64+j], gB2 = GB[128+j];
            float gC0 = GC[j], gC1 = GC[64+j], gC2 = GC[128+j];
            float gD0 = GD[j], gD1 = GD[64+j], gD2 = GD[128+j];

            GRU_STEP(gA0, gA1, gA2);
            GRU_STEP(gB0, gB1, gB2);
            GRU_STEP(gC0, gC1, gC2);
            GRU_STEP(gD0, gD1, gD2);
        }
    }

    // ---- head: out[b][j] = head_b[j] + sum_k h[k]*head_w[j][k] (fp32) ----
    float o = head_b[j];
#pragma unroll
    for (int k4 = 0; k4 < 16; ++k4) {
        float h0 = rl(h, 4*k4+0), h1 = rl(h, 4*k4+1);
        float h2 = rl(h, 4*k4+2), h3 = rl(h, 4*k4+3);
        const float* hw = head_w + j*64 + 4*k4;
        o += h0*hw[0] + h1*hw[1] + h2*hw[2] + h3*hw[3];
    }
    out[(size_t)b*64 + j] = o;
}

extern "C" void kernel_launch(void* const* d_in, const int* in_sizes, int n_in,
                              void* d_out, int out_size, void* d_ws, size_t ws_size,
                              hipStream_t stream) {
    const int*   seq      = (const int*)  d_in[0];
    const float* memory   = (const float*)d_in[1];
    const float* embed_w  = (const float*)d_in[2];
    const float* w_ih     = (const float*)d_in[3];
    const float* w_hh     = (const float*)d_in[4];
    const float* b_ih     = (const float*)d_in[5];
    const float* b_hh     = (const float*)d_in[6];
    const float* key_w    = (const float*)d_in[7];
    const float* key_b    = (const float*)d_in[8];
    const float* val_w    = (const float*)d_in[9];
    const float* val_b    = (const float*)d_in[10];
    const float* query_w  = (const float*)d_in[11];
    const float* query_b  = (const float*)d_in[12];
    const float* head_w   = (const float*)d_in[13];
    const float* head_b   = (const float*)d_in[14];

    char* ws = (char*)d_ws;
    unsigned* kT2  = (unsigned*)(ws + WS_KT);
    unsigned* vT2  = (unsigned*)(ws + WS_V);
    float*    G    = (float*)   (ws + WS_G);
    unsigned* WPhh2 = (unsigned*)(ws + WS_WPHH);
    unsigned* WR2p  = (unsigned*)(ws + WS_WR);
    float4*   KQP   = (float4*)  (ws + WS_KWP);
    float4*   VWP   = (float4*)  (ws + WS_VWP);
    float*    KQf   = (float*)   (ws + WS_KQF);
    float*    bqv   = (float*)   (ws + WS_BQ);
    float*    kqv   = (float*)   (ws + WS_KQV);
    float*    c0p   = (float*)   (ws + WS_C0);
    float*    cB    = (float*)   (ws + WS_CB);

    (void)hipFuncSetAttribute((const void*)recurrent_main,
                              hipFuncAttributeMaxDynamicSharedMemorySize,
                              (int)SMEM_BYTES);

    pack_weights<<<64, 256, 0, stream>>>(w_ih, w_hh, val_w, WPhh2, WR2p, VWP);
    fold_kq<<<64, 64, 0, stream>>>(key_w, query_w, key_b, query_b,
                                   KQf, bqv, kqv, c0p);
    pack_kq<<<4, 256, 0, stream>>>(KQf, KQP);
    build_G<<<64, 64, 0, stream>>>(embed_w, w_ih, b_ih, G);
    compute_kv<<<(B_*M_)/4, 256, 0, stream>>>(memory, bqv, val_b, KQP, VWP,
                                              kqv, c0p, kT2, vT2, cB);
    recurrent_main<<<B_, 64, SMEM_BYTES, stream>>>(seq, b_hh, head_w, head_b,
                                                   kT2, vT2, G, WPhh2, WR2p, cB,
                                                   (float*)d_out);
}